// Round 25
// baseline (141.469 us; speedup 1.0000x reference)
//
#include <hip/hip_runtime.h>
#include <hip/hip_bf16.h>
#include <stdint.h>

typedef short bf16x8 __attribute__((ext_vector_type(8)));
typedef float f32x4 __attribute__((ext_vector_type(4)));
typedef unsigned int u32x2 __attribute__((ext_vector_type(2)));

__device__ __forceinline__ uint32_t pack2f(float lo, float hi) {
  union { __hip_bfloat162 h; uint32_t u; } c;
  c.h.x = __float2bfloat16(lo);
  c.h.y = __float2bfloat16(hi);
  return c.u;
}

__device__ __forceinline__ unsigned short f32_to_bf16(float f) {
  union { __hip_bfloat16 h; unsigned short u; } c;
  c.h = __float2bfloat16(f);
  return c.u;
}

__device__ __forceinline__ float bfbits_to_f32(uint32_t hi16) {
  union { uint32_t u; float f; } c;
  c.u = hi16 << 16;
  return c.f;
}

__device__ __forceinline__ float fast_tanh(float x) {
  float e = __builtin_amdgcn_exp2f(x * 2.8853900817779268f);
  return 1.0f - 2.0f * __builtin_amdgcn_rcpf(e + 1.0f);
}

// offset-0 global_load_lds (imm-offset shifts BOTH global and LDS addresses)
#define GLD16(g, l)                                                                    \
  __builtin_amdgcn_global_load_lds((const __attribute__((address_space(1))) void*)(g), \
                                   (__attribute__((address_space(3))) void*)(l), 16, 0, 0)

#define MFMA16(a, b, c) __builtin_amdgcn_mfma_f32_16x16x32_bf16(a, b, c, 0, 0, 0)
#define SBAR0() __builtin_amdgcn_sched_barrier(0)

// ---------------- prep2: W1k transpose | qterm (convert fused into GEMM) ----------------
__global__ void prep2_kernel(const float* __restrict__ W1, unsigned short* __restrict__ W1kt,
                             const float* __restrict__ query, const float* __restrict__ b1,
                             float* __restrict__ qterm) {
  __shared__ __align__(16) unsigned char smem[16896];
  const int bid = blockIdx.x;
  const int t = threadIdx.x;
  if (bid < 256) {
    float (*tt)[65] = (float(*)[65])smem;
    const int kb = (bid & 15) * 64;
    const int jb = (bid >> 4) * 64;
    const int c = t & 63;
    const int r = t >> 6;
#pragma unroll
    for (int i = 0; i < 16; ++i) {
      const int k = i * 4 + r;
      tt[k][c] = W1[(size_t)(1024 + kb + k) * 1024 + (jb + c)];
    }
    __syncthreads();
#pragma unroll
    for (int i = 0; i < 16; ++i) {
      const int j = i * 4 + r;
      W1kt[(size_t)(jb + j) * 1024 + (kb + c)] = f32_to_bf16(tt[c][j]);
    }
  } else {
    float (*part)[64] = (float(*)[64])smem;
    const int q = bid - 256;
    const int b = q >> 4;
    const int j = (q & 15) * 64 + (t & 63);
    const int kq = t >> 6;
    const float* qp = query + b * 1024 + kq * 256;
    const float* wp = W1 + (size_t)(kq * 256) * 1024 + j;
    float acc = 0.f;
#pragma unroll 8
    for (int k = 0; k < 256; ++k) acc += qp[k] * wp[(size_t)k * 1024];
    part[kq][t & 63] = acc;
    __syncthreads();
    if (t < 64) {
      const int jj = (q & 15) * 64 + t;
      qterm[b * 1024 + jj] = b1[jj] + part[0][t] + part[1][t] + part[2][t] + part[3][t];
    }
  }
}

// ---------------- v19: fused convert + GEMM + tanh + W2-reduce ----------------
// v17 topology (single keys pass, fp32 A -> regs -> bf16 -> swizzled LDS; cg0 stores
// keysbf) with the schedule fixed: compute ds_reads issued FIRST, staging (pack/write/
// store/B-GLD/A-loads) placed between ds_read issue and MFMA so it overlaps MFMA.
// Counted drain vmcnt(8) keeps A(t+2) in flight; LAST iter drains vmcnt(0) (else
// non-cg0 blocks leave B(15) unwaited -- only 4 ops outstanding < 8).

#define V19_LOAD_A(kt_)                         \
  _Pragma("unroll") for (int i = 0; i < 8; ++i) \
      Ar[i] = *(const f32x4*)(gkeys + (size_t)i * 32768 + (kt_) * 64);

#define V19_PACK()                                \
  _Pragma("unroll") for (int i = 0; i < 8; ++i) { \
    pk[i].x = pack2f(Ar[i].x, Ar[i].y);           \
    pk[i].y = pack2f(Ar[i].z, Ar[i].w);           \
  }

#define V19_WRITE_A(Ps)                         \
  _Pragma("unroll") for (int i = 0; i < 8; ++i) \
      *(u32x2*)((Ps) + awof + i * 4096) = pk[i];

#define V19_STORE(kt_)                          \
  _Pragma("unroll") for (int i = 0; i < 8; ++i) \
      *(u32x2*)(gkbf + (size_t)i * 32768 + (kt_) * 64) = pk[i];

#define V19_STAGE_B(kt_, P)                                          \
  GLD16(gwB + (kt_) * 64 + 0 * 65536, (P) + 32768 + 0 * 8192 + t16); \
  GLD16(gwB + (kt_) * 64 + 1 * 65536, (P) + 32768 + 1 * 8192 + t16); \
  GLD16(gwB + (kt_) * 64 + 2 * 65536, (P) + 32768 + 2 * 8192 + t16); \
  GLD16(gwB + (kt_) * 64 + 3 * 65536, (P) + 32768 + 3 * 8192 + t16);

#define V19_ITER(t_, Pc, Ps, LAST)                                          \
  if (LAST) { asm volatile("s_waitcnt vmcnt(0) lgkmcnt(0)" ::: "memory"); } \
  else      { asm volatile("s_waitcnt vmcnt(8) lgkmcnt(0)" ::: "memory"); } \
  __builtin_amdgcn_s_barrier();                                             \
  SBAR0();                                                                  \
  {                                                                         \
    bf16x8 af[8], bfv[4];                                                   \
    /* kk=0 fragment ds_reads issued first */                               \
    _Pragma("unroll") for (int mf = 0; mf < 8; ++mf)                        \
        af[mf] = *(const bf16x8*)((Pc) + (abase + mf * 2048));              \
    _Pragma("unroll") for (int nf = 0; nf < 4; ++nf)                        \
        bfv[nf] = *(const bf16x8*)((Pc) + (bbase + nf * 2048));             \
    SBAR0();                                                                \
    if (!(LAST)) {                                                          \
      V19_PACK();          /* compiler waits A(t+1) loads precisely */      \
      V19_WRITE_A(Ps);                                                      \
      if (cg0) { V19_STORE((t_) + 1); }                                     \
      SBAR0();                                                              \
      V19_STAGE_B((t_) + 1, Ps);                                            \
      SBAR0();                                                              \
      if ((t_) < 14) { V19_LOAD_A((t_) + 2); }                              \
      SBAR0();                                                              \
    }                                                                       \
    __builtin_amdgcn_s_setprio(1);                                          \
    _Pragma("unroll") for (int nf = 0; nf < 4; ++nf)                        \
        _Pragma("unroll") for (int mf = 0; mf < 8; ++mf) acc[mf][nf] =      \
            MFMA16(af[mf], bfv[nf], acc[mf][nf]);                           \
    __builtin_amdgcn_s_setprio(0);                                          \
    /* kk=1 */                                                              \
    _Pragma("unroll") for (int mf = 0; mf < 8; ++mf)                        \
        af[mf] = *(const bf16x8*)((Pc) + ((abase + mf * 2048) ^ 64));       \
    _Pragma("unroll") for (int nf = 0; nf < 4; ++nf)                        \
        bfv[nf] = *(const bf16x8*)((Pc) + ((bbase + nf * 2048) ^ 64));      \
    __builtin_amdgcn_s_setprio(1);                                          \
    _Pragma("unroll") for (int nf = 0; nf < 4; ++nf)                        \
        _Pragma("unroll") for (int mf = 0; mf < 8; ++mf) acc[mf][nf] =      \
            MFMA16(af[mf], bfv[nf], acc[mf][nf]);                           \
    __builtin_amdgcn_s_setprio(0);                                          \
  }

#define V19_PAIR(t0, t1)      \
  V19_ITER(t0, P0, P1, false) \
  V19_ITER(t1, P1, P0, (t1) == 15)

__global__ __launch_bounds__(512, 1) void gemm_score_v19(
    const float* __restrict__ keys, unsigned short* __restrict__ keysbf,
    const unsigned short* __restrict__ W1kt, const float* __restrict__ qterm,
    const float* __restrict__ coverage, const float* __restrict__ W1,
    const float* __restrict__ W2, float* __restrict__ scores_part) {
  __shared__ __align__(16) unsigned char lds[135168];
  unsigned char* P0 = lds;               // A 32KB + B 32KB
  unsigned char* P1 = lds + 65536;
  float* Sred = (float*)(lds + 131072);  // 8 x 128 f32

  const int tid = threadIdx.x;
  const int bid = blockIdx.x;  // 512
  const int xcd = bid & 7;
  const int idx = bid >> 3;                // 0..63
  const int rowt = xcd * 16 + (idx >> 2);  // 0..127
  const int colgrp = idx & 3;              // 0..3
  const bool cg0 = (colgrp == 0);
  const int row0 = rowt * 256;
  const int col0 = colgrp * 256;
  const int b = row0 >> 11;
  const int w = tid >> 6;             // 0..7
  const int wm = w >> 2, wn = w & 3;  // 2 x 4
  const int lane = tid & 63;
  const int c16 = lane & 15, q4 = lane >> 4;

  // fragment-read bases (v16 layout; kk advance via XOR 64)
  const int swzc = (q4 ^ (c16 & 7)) << 4;
  const int abase = (wm * 128 + c16) * 128 + swzc;
  const int bbase = 32768 + (wn * 64 + c16) * 128 + swzc;

  // A map (v17-verified): thread covers rows (tid>>4)+i*32, k-floats (tid&15)*4
  const int ar0 = tid >> 4;  // 0..31
  const int kun = tid & 15;
  const float* gkeys = keys + (size_t)(row0 + ar0) * 1024 + kun * 4;
  unsigned short* gkbf = keysbf + (size_t)(row0 + ar0) * 1024 + kun * 4;
  const int awof = ar0 * 128 + ((((kun >> 1) ^ (ar0 & 7)) << 4) + (kun & 1) * 8);

  // B stage map (v16): row r=(tid>>3)+j*64, unit (tid&7)^(r&7)
  const int sr = tid >> 3;
  const int su = (tid & 7) ^ (sr & 7);
  const unsigned short* gwB = W1kt + (size_t)(col0 + sr) * 1024 + su * 8;
  const int t16 = tid * 16;

  f32x4 Ar[8];
  u32x2 pk[8];
  f32x4 acc[8][4];
  const f32x4 zz = {0.f, 0.f, 0.f, 0.f};
#pragma unroll
  for (int mf = 0; mf < 8; ++mf)
#pragma unroll
    for (int nf = 0; nf < 4; ++nf) acc[mf][nf] = zz;

  // prologue: A(0)->regs->P0 (+keysbf), B(0)->P0, A(1)->regs
  V19_LOAD_A(0);
  V19_PACK();
  V19_WRITE_A(P0);
  if (cg0) { V19_STORE(0); }
  SBAR0();
  V19_STAGE_B(0, P0);
  SBAR0();
  V19_LOAD_A(1);
  SBAR0();

  V19_PAIR(0, 1)
  V19_PAIR(2, 3)
  V19_PAIR(4, 5)
  V19_PAIR(6, 7)
  V19_PAIR(8, 9)
  V19_PAIR(10, 11)
  V19_PAIR(12, 13)
  V19_PAIR(14, 15)

  // ---- epilogue ----
  float covv[8][4];
#pragma unroll
  for (int mf = 0; mf < 8; ++mf)
#pragma unroll
    for (int r = 0; r < 4; ++r)
      covv[mf][r] = coverage[row0 + wm * 128 + mf * 16 + q4 * 4 + r];

  float p_part[8][4];
#pragma unroll
  for (int mf = 0; mf < 8; ++mf)
#pragma unroll
    for (int r = 0; r < 4; ++r) p_part[mf][r] = 0.f;

#pragma unroll
  for (int nf = 0; nf < 4; ++nf) {
    const int col = col0 + wn * 64 + nf * 16 + c16;
    const float qt = qterm[b * 1024 + col];
    const float w1c = W1[(size_t)2048 * 1024 + col];
    const float w2 = W2[col];
#pragma unroll
    for (int mf = 0; mf < 8; ++mf)
#pragma unroll
      for (int r = 0; r < 4; ++r) {
        float v = acc[mf][nf][r] + qt + covv[mf][r] * w1c;
        p_part[mf][r] += fast_tanh(v) * w2;
      }
  }

#pragma unroll
  for (int mf = 0; mf < 8; ++mf)
#pragma unroll
    for (int r = 0; r < 4; ++r) {
      float p = p_part[mf][r];
      p += __shfl_xor(p, 1);
      p += __shfl_xor(p, 2);
      p += __shfl_xor(p, 4);
      p += __shfl_xor(p, 8);
      if (c16 == 0) Sred[w * 128 + mf * 16 + q4 * 4 + r] = p;
    }
  __syncthreads();
  if (tid < 256) {
    const int wmv = tid >> 7, rl = tid & 127;
    float s = Sred[(wmv * 4 + 0) * 128 + rl] + Sred[(wmv * 4 + 1) * 128 + rl] +
              Sred[(wmv * 4 + 2) * 128 + rl] + Sred[(wmv * 4 + 3) * 128 + rl];
    scores_part[(size_t)colgrp * 32768 + row0 + tid] = s;
  }
}

// ---------------- fused softmax + ctx_part ----------------
__global__ void ctxpre_fused(const unsigned short* __restrict__ keysbf,
                             const float* __restrict__ sp, float* __restrict__ att,
                             float* __restrict__ ctx_part) {
  __shared__ float sc[2048];
  __shared__ float red[4];
  __shared__ float att_s[128];
  const int b = blockIdx.x;     // 16
  const int sl = blockIdx.y;    // 16 slices of 128 rows
  const int tid = threadIdx.x;  // 256
  float mx = -1e30f;
  for (int l = tid; l < 2048; l += 256) {
    float v = 0.f;
#pragma unroll
    for (int g = 0; g < 4; ++g) v += sp[(size_t)g * 32768 + b * 2048 + l];
    sc[l] = v;
    mx = fmaxf(mx, v);
  }
#pragma unroll
  for (int o = 1; o < 64; o <<= 1) mx = fmaxf(mx, __shfl_xor(mx, o));
  if ((tid & 63) == 0) red[tid >> 6] = mx;
  __syncthreads();
  mx = fmaxf(fmaxf(red[0], red[1]), fmaxf(red[2], red[3]));
  __syncthreads();
  float sum = 0.f;
  for (int l = tid; l < 2048; l += 256) sum += __expf(sc[l] - mx);
#pragma unroll
  for (int o = 1; o < 64; o <<= 1) sum += __shfl_xor(sum, o);
  if ((tid & 63) == 0) red[tid >> 6] = sum;
  __syncthreads();
  const float inv = 1.0f / (red[0] + red[1] + red[2] + red[3]);
  if (tid < 128) {
    const float a = __expf(sc[sl * 128 + tid] - mx) * inv;
    att_s[tid] = a;
    att[b * 2048 + sl * 128 + tid] = a;
  }
  __syncthreads();

  const unsigned short* kb = keysbf + ((size_t)b * 2048 + sl * 128) * 1024 + tid * 4;
  f32x4 acc = {0.f, 0.f, 0.f, 0.f};
#pragma unroll 4
  for (int l = 0; l < 128; ++l) {
    u32x2 v = *(const u32x2*)(kb + (size_t)l * 1024);
    const float al = att_s[l];
    acc.x += bfbits_to_f32(v.x & 0xFFFFu) * al;
    acc.y += bfbits_to_f32(v.x >> 16) * al;
    acc.z += bfbits_to_f32(v.y & 0xFFFFu) * al;
    acc.w += bfbits_to_f32(v.y >> 16) * al;
  }
  *(f32x4*)(ctx_part + ((size_t)(sl * 16 + b)) * 1024 + tid * 4) = acc;
}

// ---------------- fused: ctx_pre reduce (into LDS) + context matmul ----------------
__global__ void ctx2_kernel(const float* __restrict__ ctx_part, const float* __restrict__ Wr,
                            float* __restrict__ out) {
  __shared__ float cpre[1024];
  __shared__ float part[4][64];
  const int hb = blockIdx.x;  // 8
  const int b = blockIdx.y;   // 16
  const int t = threadIdx.x;  // 256
#pragma unroll
  for (int jj = 0; jj < 4; ++jj) {
    const int j = jj * 256 + t;
    float s = 0.f;
#pragma unroll
    for (int sl = 0; sl < 16; ++sl) s += ctx_part[((size_t)(sl * 16 + b)) * 1024 + j];
    cpre[j] = s;
  }
  __syncthreads();
  const int h = hb * 64 + (t & 63);
  const int jq = t >> 6;
  const float* wp = Wr + (size_t)(jq * 256) * 512 + h;
  float acc = 0.f;
#pragma unroll 8
  for (int k = 0; k < 256; ++k) acc += cpre[jq * 256 + k] * wp[(size_t)k * 512];
  part[jq][t & 63] = acc;
  __syncthreads();
  if (t < 64)
    out[b * 512 + hb * 64 + t] = part[0][t] + part[1][t] + part[2][t] + part[3][t];
}

extern "C" void kernel_launch(void* const* d_in, const int* in_sizes, int n_in, void* d_out,
                              int out_size, void* d_ws, size_t ws_size, hipStream_t stream) {
  const float* query = (const float*)d_in[0];     // (16,1,1024)
  const float* keys = (const float*)d_in[1];      // (16,2048,1024)
  const float* coverage = (const float*)d_in[2];  // (16,2048,1)
  const float* W1 = (const float*)d_in[3];        // (2049,1024)
  const float* b1 = (const float*)d_in[4];        // (1024,)
  const float* W2 = (const float*)d_in[5];        // (1024,1)
  const float* Wr = (const float*)d_in[6];        // (1024,512)
  float* out = (float*)d_out;
  char* ws = (char*)d_ws;

  float* scores_part = (float*)ws;          // 4*32768 f32 = 512KB @ 0
  float* ctx_part = (float*)(ws + 524288);  // 16*16*1024 f32 = 1MB
  float* qterm = (float*)(ws + 1638400);    // 16384 f32
  unsigned short* W1kt = (unsigned short*)(ws + 1703936);    // 1M bf16 (2MB)
  unsigned short* keysbf = (unsigned short*)(ws + 3801088);  // 32M bf16 (64MB)

  float* context_out = out;     // 16*512
  float* att_out = out + 8192;  // 16*2048

  prep2_kernel<<<dim3(512), dim3(256), 0, stream>>>(W1, W1kt, query, b1, qterm);
  gemm_score_v19<<<dim3(512), dim3(512), 0, stream>>>(keys, keysbf, W1kt, qterm, coverage, W1,
                                                      W2, scores_part);
  ctxpre_fused<<<dim3(16, 16), dim3(256), 0, stream>>>(keysbf, scores_part, att_out, ctx_part);
  ctx2_kernel<<<dim3(8, 16), dim3(256), 0, stream>>>(ctx_part, Wr, context_out);
}

// Round 26
// 131.356 us; speedup vs baseline: 1.0770x; 1.0770x over previous
//
#include <hip/hip_runtime.h>
#include <hip/hip_bf16.h>
#include <stdint.h>

typedef short bf16x8 __attribute__((ext_vector_type(8)));
typedef float f32x4 __attribute__((ext_vector_type(4)));
typedef unsigned int u32x2 __attribute__((ext_vector_type(2)));
typedef unsigned int u32x4 __attribute__((ext_vector_type(4)));

__device__ __forceinline__ uint32_t pack2f(float lo, float hi) {
  union { __hip_bfloat162 h; uint32_t u; } c;
  c.h.x = __float2bfloat16(lo);
  c.h.y = __float2bfloat16(hi);
  return c.u;
}

__device__ __forceinline__ unsigned short f32_to_bf16(float f) {
  union { __hip_bfloat16 h; unsigned short u; } c;
  c.h = __float2bfloat16(f);
  return c.u;
}

__device__ __forceinline__ float bfbits_to_f32(uint32_t hi16) {
  union { uint32_t u; float f; } c;
  c.u = hi16 << 16;
  return c.f;
}

__device__ __forceinline__ float fast_tanh(float x) {
  float e = __builtin_amdgcn_exp2f(x * 2.8853900817779268f);
  return 1.0f - 2.0f * __builtin_amdgcn_rcpf(e + 1.0f);
}

// offset-0 global_load_lds (imm-offset shifts BOTH global and LDS addresses)
#define GLD16(g, l)                                                                    \
  __builtin_amdgcn_global_load_lds((const __attribute__((address_space(1))) void*)(g), \
                                   (__attribute__((address_space(3))) void*)(l), 16, 0, 0)

#define MFMA16(a, b, c) __builtin_amdgcn_mfma_f32_16x16x32_bf16(a, b, c, 0, 0, 0)
#define SBAR0() __builtin_amdgcn_sched_barrier(0)

// ---------------- fused prep: W1k transpose | qterm | convert keys->bf16 ----------------
// Convert: per-WAVE pipelined LDS-DMA. Each wave owns 16KB processed as 4 chunks of 4KB
// through a 3-deep private LDS buffer ring; counted vmcnt drains (never 0 mid-loop, no
// __syncthreads -- readback is within the issuing wave). Deep DMA queue stays full:
// this is the one untried cell (all prior ~75us variants serialized via VGPR cap,
// full drains, or sub-16B global sides). Both global sides 16B/lane.
__global__ void prep_kernel(const float* __restrict__ keys, unsigned short* __restrict__ keysbf,
                            const float* __restrict__ W1, unsigned short* __restrict__ W1kt,
                            const float* __restrict__ query, const float* __restrict__ b1,
                            float* __restrict__ qterm) {
  __shared__ __align__(16) unsigned char smem[49152];
  const int bid = blockIdx.x;
  const int t = threadIdx.x;
  if (bid < 256) {
    float (*tt)[65] = (float(*)[65])smem;
    const int kb = (bid & 15) * 64;
    const int jb = (bid >> 4) * 64;
    const int c = t & 63;
    const int r = t >> 6;
#pragma unroll
    for (int i = 0; i < 16; ++i) {
      const int k = i * 4 + r;
      tt[k][c] = W1[(size_t)(1024 + kb + k) * 1024 + (jb + c)];
    }
    __syncthreads();
#pragma unroll
    for (int i = 0; i < 16; ++i) {
      const int j = i * 4 + r;
      W1kt[(size_t)(jb + j) * 1024 + (kb + c)] = f32_to_bf16(tt[c][j]);
    }
  } else if (bid < 512) {
    float (*part)[64] = (float(*)[64])smem;
    const int q = bid - 256;
    const int b = q >> 4;
    const int j = (q & 15) * 64 + (t & 63);
    const int kq = t >> 6;
    const float* qp = query + b * 1024 + kq * 256;
    const float* wp = W1 + (size_t)(kq * 256) * 1024 + j;
    float acc = 0.f;
#pragma unroll 8
    for (int k = 0; k < 256; ++k) acc += qp[k] * wp[(size_t)k * 1024];
    part[kq][t & 63] = acc;
    __syncthreads();
    if (t < 64) {
      const int jj = (q & 15) * 64 + t;
      qterm[b * 1024 + jj] = b1[jj] + part[0][t] + part[1][t] + part[2][t] + part[3][t];
    }
  } else {
    // convert: block covers 16384 floats; each wave 4096 floats in 4 chunks of 1024.
    unsigned char* wbuf = smem + (t >> 6) * 12288;  // 3 x 4KB ring per wave
    const int l = t & 63;
    const size_t wbase = (size_t)(bid - 512) * 16384 + (size_t)(t >> 6) * 4096;
    const float* src = keys + wbase;
    unsigned short* dst = keysbf + wbase;
    // chunk load: call i, lane l loads floats c*1024 + i*256 + l*4 -> LDS i*1024 + l*16
#define CGLD(c_, B_)                                         \
  _Pragma("unroll") for (int i = 0; i < 4; ++i)              \
      GLD16(src + (c_) * 1024 + i * 256 + l * 4, (B_) + i * 1024 + l * 16);
    // pack+store: lane l reads chunk elements [l*16, l*16+16) (LDS bytes l*64..+64),
    // stores 2 x u32x4 at dst + c*1024 + l*16 (16B/lane contiguous both stores)
#define CPACK(c_, B_)                                        \
  {                                                          \
    f32x4 a0 = *(const f32x4*)((B_) + l * 64);               \
    f32x4 a1 = *(const f32x4*)((B_) + l * 64 + 16);          \
    f32x4 a2 = *(const f32x4*)((B_) + l * 64 + 32);          \
    f32x4 a3 = *(const f32x4*)((B_) + l * 64 + 48);          \
    u32x4 o0, o1;                                            \
    o0.x = pack2f(a0.x, a0.y); o0.y = pack2f(a0.z, a0.w);    \
    o0.z = pack2f(a1.x, a1.y); o0.w = pack2f(a1.z, a1.w);    \
    o1.x = pack2f(a2.x, a2.y); o1.y = pack2f(a2.z, a2.w);    \
    o1.z = pack2f(a3.x, a3.y); o1.w = pack2f(a3.z, a3.w);    \
    *(u32x4*)(dst + (c_) * 1024 + l * 16) = o0;              \
    *(u32x4*)(dst + (c_) * 1024 + l * 16 + 8) = o1;          \
  }
    CGLD(0, wbuf)
    CGLD(1, wbuf + 4096)
    asm volatile("s_waitcnt vmcnt(4)" ::: "memory");  // G0 done; G1 in flight
    CPACK(0, wbuf)
    CGLD(2, wbuf + 8192)
    asm volatile("s_waitcnt vmcnt(6)" ::: "memory");  // G1 done; S0(2)+G2(4) in flight
    CPACK(1, wbuf + 4096)
    CGLD(3, wbuf)                                     // buf0 free (pack0 completed)
    asm volatile("s_waitcnt vmcnt(6)" ::: "memory");  // G2 done; S1(2)+G3(4) in flight
    CPACK(2, wbuf + 8192)
    asm volatile("s_waitcnt vmcnt(2)" ::: "memory");  // G3 done; S2(2) in flight
    CPACK(3, wbuf)
#undef CGLD
#undef CPACK
  }
}

// ---------------- fused GEMM + tanh + W2-reduce (v16b: BK=64 superbuffers, 16 barriers) ----------------
#define V16_STAGE(kt_, P)                                            \
  GLD16(gkA + (kt_) * 64 + 0 * 65536, (P) + 0 * 8192 + t16);         \
  GLD16(gwB + (kt_) * 64 + 0 * 65536, (P) + 32768 + 0 * 8192 + t16); \
  GLD16(gkA + (kt_) * 64 + 1 * 65536, (P) + 1 * 8192 + t16);         \
  GLD16(gwB + (kt_) * 64 + 1 * 65536, (P) + 32768 + 1 * 8192 + t16); \
  GLD16(gkA + (kt_) * 64 + 2 * 65536, (P) + 2 * 8192 + t16);         \
  GLD16(gwB + (kt_) * 64 + 2 * 65536, (P) + 32768 + 2 * 8192 + t16); \
  GLD16(gkA + (kt_) * 64 + 3 * 65536, (P) + 3 * 8192 + t16);         \
  GLD16(gwB + (kt_) * 64 + 3 * 65536, (P) + 32768 + 3 * 8192 + t16);

#define V16_COMPUTE(P)                                                           \
  _Pragma("unroll") for (int kk = 0; kk < 2; ++kk) {                             \
    bf16x8 af[8], bfv[4];                                                        \
    _Pragma("unroll") for (int mf = 0; mf < 8; ++mf)                             \
        af[mf] = *(const bf16x8*)((P) + ((abase + mf * 2048) ^ (kk * 64)));      \
    _Pragma("unroll") for (int nf = 0; nf < 4; ++nf)                             \
        bfv[nf] = *(const bf16x8*)((P) + ((bbase + nf * 2048) ^ (kk * 64)));     \
    __builtin_amdgcn_s_setprio(1);                                               \
    _Pragma("unroll") for (int nf = 0; nf < 4; ++nf)                             \
        _Pragma("unroll") for (int mf = 0; mf < 8; ++mf) acc[mf][nf] =           \
            MFMA16(af[mf], bfv[nf], acc[mf][nf]);                                \
    __builtin_amdgcn_s_setprio(0);                                               \
  }

#define V16_ITER(t_, Pc, Ps, LAST)                            \
  asm volatile("s_waitcnt vmcnt(0) lgkmcnt(0)" ::: "memory"); \
  __builtin_amdgcn_s_barrier();                               \
  SBAR0();                                                    \
  if (!(LAST)) { V16_STAGE((t_) + 1, Ps); }                   \
  SBAR0();                                                    \
  V16_COMPUTE(Pc);

#define V16_PAIR(t0, t1)      \
  V16_ITER(t0, P0, P1, false) \
  V16_ITER(t1, P1, P0, (t1) == 15)

__global__ __launch_bounds__(512, 2) void gemm_score_v16(
    const unsigned short* __restrict__ keysbf, const unsigned short* __restrict__ W1kt,
    const float* __restrict__ qterm, const float* __restrict__ coverage,
    const float* __restrict__ W1, const float* __restrict__ W2,
    float* __restrict__ scores_part) {
  __shared__ __align__(16) unsigned char lds[135168];
  unsigned char* P0 = lds;
  unsigned char* P1 = lds + 65536;
  float* Sred = (float*)(lds + 131072);

  const int tid = threadIdx.x;
  const int bid = blockIdx.x;  // 512
  const int xcd = bid & 7;
  const int idx = bid >> 3;
  const int rowt = xcd * 16 + (idx >> 2);
  const int colgrp = idx & 3;
  const int row0 = rowt * 256;
  const int col0 = colgrp * 256;
  const int b = row0 >> 11;
  const int w = tid >> 6;
  const int wm = w >> 2, wn = w & 3;
  const int lane = tid & 63;
  const int c16 = lane & 15, q4 = lane >> 4;

  const int swzc = (q4 ^ (c16 & 7)) << 4;
  const int abase = (wm * 128 + c16) * 128 + swzc;
  const int bbase = 32768 + (wn * 64 + c16) * 128 + swzc;

  const int sr = tid >> 3;
  const int su = (tid & 7) ^ (sr & 7);
  const unsigned short* gkA = keysbf + (size_t)(row0 + sr) * 1024 + su * 8;
  const unsigned short* gwB = W1kt + (size_t)(col0 + sr) * 1024 + su * 8;
  const int t16 = tid * 16;

  f32x4 acc[8][4];
  const f32x4 zz = {0.f, 0.f, 0.f, 0.f};
#pragma unroll
  for (int mf = 0; mf < 8; ++mf)
#pragma unroll
    for (int nf = 0; nf < 4; ++nf) acc[mf][nf] = zz;

  V16_STAGE(0, P0);

  V16_PAIR(0, 1)
  V16_PAIR(2, 3)
  V16_PAIR(4, 5)
  V16_PAIR(6, 7)
  V16_PAIR(8, 9)
  V16_PAIR(10, 11)
  V16_PAIR(12, 13)
  V16_PAIR(14, 15)

  float covv[8][4];
#pragma unroll
  for (int mf = 0; mf < 8; ++mf)
#pragma unroll
    for (int r = 0; r < 4; ++r)
      covv[mf][r] = coverage[row0 + wm * 128 + mf * 16 + q4 * 4 + r];

  float p_part[8][4];
#pragma unroll
  for (int mf = 0; mf < 8; ++mf)
#pragma unroll
    for (int r = 0; r < 4; ++r) p_part[mf][r] = 0.f;

#pragma unroll
  for (int nf = 0; nf < 4; ++nf) {
    const int col = col0 + wn * 64 + nf * 16 + c16;
    const float qt = qterm[b * 1024 + col];
    const float w1c = W1[(size_t)2048 * 1024 + col];
    const float w2 = W2[col];
#pragma unroll
    for (int mf = 0; mf < 8; ++mf)
#pragma unroll
      for (int r = 0; r < 4; ++r) {
        float v = acc[mf][nf][r] + qt + covv[mf][r] * w1c;
        p_part[mf][r] += fast_tanh(v) * w2;
      }
  }

#pragma unroll
  for (int mf = 0; mf < 8; ++mf)
#pragma unroll
    for (int r = 0; r < 4; ++r) {
      float p = p_part[mf][r];
      p += __shfl_xor(p, 1);
      p += __shfl_xor(p, 2);
      p += __shfl_xor(p, 4);
      p += __shfl_xor(p, 8);
      if (c16 == 0) Sred[w * 128 + mf * 16 + q4 * 4 + r] = p;
    }
  __syncthreads();
  if (tid < 256) {
    const int wmv = tid >> 7, rl = tid & 127;
    float s = Sred[(wmv * 4 + 0) * 128 + rl] + Sred[(wmv * 4 + 1) * 128 + rl] +
              Sred[(wmv * 4 + 2) * 128 + rl] + Sred[(wmv * 4 + 3) * 128 + rl];
    scores_part[(size_t)colgrp * 32768 + row0 + tid] = s;
  }
}

// ---------------- fused softmax + ctx_part ----------------
__global__ void ctxpre_fused(const unsigned short* __restrict__ keysbf,
                             const float* __restrict__ sp, float* __restrict__ att,
                             float* __restrict__ ctx_part) {
  __shared__ float sc[2048];
  __shared__ float red[4];
  __shared__ float att_s[128];
  const int b = blockIdx.x;
  const int sl = blockIdx.y;
  const int tid = threadIdx.x;
  float mx = -1e30f;
  for (int l = tid; l < 2048; l += 256) {
    float v = 0.f;
#pragma unroll
    for (int g = 0; g < 4; ++g) v += sp[(size_t)g * 32768 + b * 2048 + l];
    sc[l] = v;
    mx = fmaxf(mx, v);
  }
#pragma unroll
  for (int o = 1; o < 64; o <<= 1) mx = fmaxf(mx, __shfl_xor(mx, o));
  if ((tid & 63) == 0) red[tid >> 6] = mx;
  __syncthreads();
  mx = fmaxf(fmaxf(red[0], red[1]), fmaxf(red[2], red[3]));
  __syncthreads();
  float sum = 0.f;
  for (int l = tid; l < 2048; l += 256) sum += __expf(sc[l] - mx);
#pragma unroll
  for (int o = 1; o < 64; o <<= 1) sum += __shfl_xor(sum, o);
  if ((tid & 63) == 0) red[tid >> 6] = sum;
  __syncthreads();
  const float inv = 1.0f / (red[0] + red[1] + red[2] + red[3]);
  if (tid < 128) {
    const float a = __expf(sc[sl * 128 + tid] - mx) * inv;
    att_s[tid] = a;
    att[b * 2048 + sl * 128 + tid] = a;
  }
  __syncthreads();

  const unsigned short* kb = keysbf + ((size_t)b * 2048 + sl * 128) * 1024 + tid * 4;
  f32x4 acc = {0.f, 0.f, 0.f, 0.f};
#pragma unroll 4
  for (int l = 0; l < 128; ++l) {
    u32x2 v = *(const u32x2*)(kb + (size_t)l * 1024);
    const float al = att_s[l];
    acc.x += bfbits_to_f32(v.x & 0xFFFFu) * al;
    acc.y += bfbits_to_f32(v.x >> 16) * al;
    acc.z += bfbits_to_f32(v.y & 0xFFFFu) * al;
    acc.w += bfbits_to_f32(v.y >> 16) * al;
  }
  *(f32x4*)(ctx_part + ((size_t)(sl * 16 + b)) * 1024 + tid * 4) = acc;
}

// ---------------- fused: ctx_pre reduce (into LDS) + context matmul ----------------
__global__ void ctx2_kernel(const float* __restrict__ ctx_part, const float* __restrict__ Wr,
                            float* __restrict__ out) {
  __shared__ float cpre[1024];
  __shared__ float part[4][64];
  const int hb = blockIdx.x;
  const int b = blockIdx.y;
  const int t = threadIdx.x;
#pragma unroll
  for (int jj = 0; jj < 4; ++jj) {
    const int j = jj * 256 + t;
    float s = 0.f;
#pragma unroll
    for (int sl = 0; sl < 16; ++sl) s += ctx_part[((size_t)(sl * 16 + b)) * 1024 + j];
    cpre[j] = s;
  }
  __syncthreads();
  const int h = hb * 64 + (t & 63);
  const int jq = t >> 6;
  const float* wp = Wr + (size_t)(jq * 256) * 512 + h;
  float acc = 0.f;
#pragma unroll 8
  for (int k = 0; k < 256; ++k) acc += cpre[jq * 256 + k] * wp[(size_t)k * 512];
  part[jq][t & 63] = acc;
  __syncthreads();
  if (t < 64)
    out[b * 512 + hb * 64 + t] = part[0][t] + part[1][t] + part[2][t] + part[3][t];
}

extern "C" void kernel_launch(void* const* d_in, const int* in_sizes, int n_in, void* d_out,
                              int out_size, void* d_ws, size_t ws_size, hipStream_t stream) {
  const float* query = (const float*)d_in[0];     // (16,1,1024)
  const float* keys = (const float*)d_in[1];      // (16,2048,1024)
  const float* coverage = (const float*)d_in[2];  // (16,2048,1)
  const float* W1 = (const float*)d_in[3];        // (2049,1024)
  const float* b1 = (const float*)d_in[4];        // (1024,)
  const float* W2 = (const float*)d_in[5];        // (1024,1)
  const float* Wr = (const float*)d_in[6];        // (1024,512)
  float* out = (float*)d_out;
  char* ws = (char*)d_ws;

  float* scores_part = (float*)ws;          // 4*32768 f32 = 512KB @ 0
  float* ctx_part = (float*)(ws + 524288);  // 16*16*1024 f32 = 1MB
  float* qterm = (float*)(ws + 1638400);    // 16384 f32
  unsigned short* W1kt = (unsigned short*)(ws + 1703936);    // 1M bf16 (2MB)
  unsigned short* keysbf = (unsigned short*)(ws + 3801088);  // 32M bf16 (64MB)

  float* context_out = out;     // 16*512
  float* att_out = out + 8192;  // 16*2048

  prep_kernel<<<dim3(2560), dim3(256), 0, stream>>>(keys, keysbf, W1, W1kt, query, b1, qterm);
  gemm_score_v16<<<dim3(512), dim3(512), 0, stream>>>(keysbf, W1kt, qterm, coverage, W1, W2,
                                                      scores_part);
  ctxpre_fused<<<dim3(16, 16), dim3(256), 0, stream>>>(keysbf, scores_part, att_out, ctx_part);
  ctx2_kernel<<<dim3(8, 16), dim3(256), 0, stream>>>(ctx_part, Wr, context_out);
}